// Round 7
// baseline (666.944 us; speedup 1.0000x reference)
//
#include <hip/hip_runtime.h>
#include <math.h>

// FrustumPointNetLoss for MI355X (gfx950).
//
// R7 = R6 with compile fix: __builtin_nontemporal_load requires clang
//     ext_vector types, not HIP_vector_type structs (int2). Use vi2.
//
// R6: (1) non-temporal loads on BOTH logits (128 MB) and labels (64 MB) --
//     all big-stream traffic goes straight to HBM, no L3 lookup/retention
//     pressure (A/B test of the "mixed-routing vs read-path ceiling" theory;
//     R5 backs out to ~5.0 TB/s effective read).
//     (2) finalize fused via last-block completion counter (release fence ->
//     atomicAdd -> acquire fence); saves one dispatch + inter-kernel gap.
//
// ws layout (doubles):
//   [0 .. 4096)        mask-loss per-block partials
//   [4096 .. 4208)     batch-loss per-block partials (16 blocks x 7 sums)
//   [4224]             completion counter (unsigned, re-zeroed each call)

constexpr int kNH = 12;
constexpr int kNS = 6;
constexpr int kBS = 4096;
constexpr int kNP = 4096;
constexpr float kPI = 3.14159265358979323846f;

constexpr int kTPB = 256;
constexpr int kMaskBlocks = 4096;
constexpr int kF4 = (kBS * kNP) / 2;             // 8,388,608 float4s (2 rows each)
constexpr int kMaskThreads = kMaskBlocks * kTPB; // 1,048,576
constexpr int kF4PerThread = kF4 / kMaskThreads; // 8
static_assert(kF4PerThread * kMaskThreads == kF4, "exact cover");

constexpr int kBatchBlocks = kBS / kTPB;          // 16
constexpr int kGrid = kMaskBlocks + kBatchBlocks; // 4112

typedef float vf4 __attribute__((ext_vector_type(4)));
typedef int vi2 __attribute__((ext_vector_type(2)));

__device__ __forceinline__ float wave_sum(float v) {
#pragma unroll
    for (int off = 32; off > 0; off >>= 1) v += __shfl_down(v, off, 64);
    return v;
}

__device__ __forceinline__ double wave_sum_d(double v) {
#pragma unroll
    for (int off = 32; off > 0; off >>= 1) v += __shfl_down(v, off, 64);
    return v;
}

__device__ __forceinline__ float huber_el(float e, float d) {
    float a = fabsf(e);
    float q = fminf(a, d);
    return 0.5f * q * q + d * (a - q);
}

// 2-class NLL: lse(s0,s1) - s_correct = softplus(s_other - s_correct)
__device__ __forceinline__ float row_nll2(float s0, float s1, int lb) {
    float x = lb ? (s0 - s1) : (s1 - s0);
    return fmaxf(x, 0.f) + __logf(1.f + __expf(-fabsf(x)));
}

__device__ void batch_loss_body(
        int bid,
        const float* __restrict__ center, const float* __restrict__ center_label,
        const float* __restrict__ stage1_center,
        const float* __restrict__ heading_scores,
        const float* __restrict__ hres_norm, const float* __restrict__ hres,
        const int* __restrict__ hcls_label, const float* __restrict__ hres_label,
        const float* __restrict__ size_scores,
        const float* __restrict__ sres_norm, const float* __restrict__ sres,
        const int* __restrict__ scls_label, const float* __restrict__ sres_label,
        const float* __restrict__ anchors, double* __restrict__ bpartials) {
    const int b = bid * kTPB + threadIdx.x;
    float v[7];  // center, stage1, hclass, hres, sclass, sres, corners
#pragma unroll
    for (int j = 0; j < 7; ++j) v[j] = 0.f;
    {
        const float cx = center[3 * b], cy = center[3 * b + 1], cz = center[3 * b + 2];
        const float glx = center_label[3 * b], gly = center_label[3 * b + 1],
                    glz = center_label[3 * b + 2];
        {
            float dx = cx - glx, dy = cy - gly, dz = cz - glz;
            v[0] = huber_el(sqrtf(dx * dx + dy * dy + dz * dz), 2.0f);
            float ex = cx - stage1_center[3 * b];
            float ey = cy - stage1_center[3 * b + 1];
            float ez = cz - stage1_center[3 * b + 2];
            v[1] = huber_el(sqrtf(ex * ex + ey * ey + ez * ez), 1.0f);
        }
        const int hc = hcls_label[b];
        const int sc = scls_label[b];
        {
            float m = -1e30f;
            for (int i = 0; i < kNH; ++i) m = fmaxf(m, heading_scores[b * kNH + i]);
            float se = 0.f;
            for (int i = 0; i < kNH; ++i) se += __expf(heading_scores[b * kNH + i] - m);
            v[2] = m + __logf(se) - heading_scores[b * kNH + hc];
        }
        {
            float m = -1e30f;
            for (int i = 0; i < kNS; ++i) m = fmaxf(m, size_scores[b * kNS + i]);
            float se = 0.f;
            for (int i = 0; i < kNS; ++i) se += __expf(size_scores[b * kNS + i] - m);
            v[4] = m + __logf(se) - size_scores[b * kNS + sc];
        }
        v[3] = huber_el(hres_norm[b * kNH + hc] - hres_label[b] * ((float)kNH / kPI), 1.0f);
        const float a0 = anchors[sc * 3 + 0];
        const float a1 = anchors[sc * 3 + 1];
        const float a2 = anchors[sc * 3 + 2];
        {
            float e0 = sres_label[3 * b + 0] / a0 - sres_norm[(b * kNS + sc) * 3 + 0];
            float e1 = sres_label[3 * b + 1] / a1 - sres_norm[(b * kNS + sc) * 3 + 1];
            float e2 = sres_label[3 * b + 2] / a2 - sres_norm[(b * kNS + sc) * 3 + 2];
            v[5] = huber_el(sqrtf(e0 * e0 + e1 * e1 + e2 * e2), 1.0f);
        }
        {
            const float bin = (float)hc * (2.0f * kPI / (float)kNH);
            const float hp = hres[b * kNH + hc] + bin;
            const float hg = hres_label[b] + bin;
            const float lp = a0 + 2.f * sres[(b * kNS + sc) * 3 + 0];
            const float wp = a1 + 2.f * sres[(b * kNS + sc) * 3 + 1];
            const float tp = a2 + 2.f * sres[(b * kNS + sc) * 3 + 2];
            const float lg = a0 + sres_label[3 * b + 0];
            const float wg = a1 + sres_label[3 * b + 1];
            const float tg = a2 + sres_label[3 * b + 2];
            const float cp = cosf(hp), sp = sinf(hp);
            const float cg = cosf(hg), sg = sinf(hg);
            const float SX[8] = {1, 1, -1, -1, 1, 1, -1, -1};
            const float SY[8] = {1, 1, 1, 1, -1, -1, -1, -1};
            const float SZ[8] = {1, -1, -1, 1, 1, -1, -1, 1};
            float cl = 0.f;
#pragma unroll
            for (int k = 0; k < 8; ++k) {
                float plx = 0.5f * lp * SX[k], ply = 0.5f * tp * SY[k], plz = 0.5f * wp * SZ[k];
                float px = cp * plx + sp * plz + cx;
                float py = ply + cy;
                float pz = -sp * plx + cp * plz + cz;
                float qlx = 0.5f * lg * SX[k], qly = 0.5f * tg * SY[k], qlz = 0.5f * wg * SZ[k];
                float rx = cg * qlx + sg * qlz;
                float rz = -sg * qlx + cg * qlz;
                float dgy = py - (qly + gly);
                float d1x = px - (rx + glx), d1z = pz - (rz + glz);
                float d2x = px - (-rx + glx), d2z = pz - (-rz + glz);
                float n1 = sqrtf(d1x * d1x + dgy * dgy + d1z * d1z);
                float n2 = sqrtf(d2x * d2x + dgy * dgy + d2z * d2z);
                cl += huber_el(fminf(n1, n2), 1.0f);
            }
            v[6] = cl;
        }
    }
    __shared__ float s[4][7];
#pragma unroll
    for (int j = 0; j < 7; ++j) {
        float r = wave_sum(v[j]);
        if ((threadIdx.x & 63) == 0) s[threadIdx.x >> 6][j] = r;
    }
    __syncthreads();
    if (threadIdx.x == 0) {
#pragma unroll
        for (int j = 0; j < 7; ++j)
            bpartials[bid * 7 + j] = (double)(s[0][j] + s[1][j] + s[2][j] + s[3][j]);
    }
}

// Block-wide final reduction: reads all partials, writes the 9 outputs.
__device__ void finalize_body(const double* __restrict__ partials,
                              const double* __restrict__ bpartials,
                              float* __restrict__ out) {
    double acc = 0.0;
#pragma unroll
    for (int i = 0; i < kMaskBlocks / kTPB; ++i)
        acc += partials[threadIdx.x + i * kTPB];
    acc = wave_sum_d(acc);
    __shared__ double s[4];
    if ((threadIdx.x & 63) == 0) s[threadIdx.x >> 6] = acc;
    __syncthreads();
    if (threadIdx.x == 0) {
        const double mask_sum = s[0] + s[1] + s[2] + s[3];
        double bsum[7] = {0, 0, 0, 0, 0, 0, 0};
        for (int blk = 0; blk < kBatchBlocks; ++blk)
#pragma unroll
            for (int j = 0; j < 7; ++j) bsum[j] += bpartials[blk * 7 + j];
        const double inv_rows = 1.0 / ((double)kBS * (double)kNP);
        const double inv_bs = 1.0 / (double)kBS;
        float mask_l = (float)(mask_sum * inv_rows);
        float center_l = (float)(bsum[0] * inv_bs);
        float stage1_l = (float)(bsum[1] * inv_bs);
        float hclass_l = (float)(bsum[2] * inv_bs);
        float hres_l20 = (float)(bsum[3] * inv_bs * 20.0);
        float sclass_l = (float)(bsum[4] * inv_bs);
        float sres_l20 = (float)(bsum[5] * inv_bs * 20.0);
        float corners10 = (float)(bsum[6] * inv_bs * (1.0 / 8.0) * 10.0);
        float total = mask_l + center_l + hclass_l + sclass_l + hres_l20 + sres_l20 +
                      stage1_l + corners10;
        out[0] = total;
        out[1] = mask_l;
        out[2] = center_l;
        out[3] = hclass_l;
        out[4] = sclass_l;
        out[5] = hres_l20;
        out[6] = sres_l20;
        out[7] = stage1_l;
        out[8] = corners10;
    }
}

__global__ __launch_bounds__(256) void fused_loss_kernel(
        const float* __restrict__ logits, const int* __restrict__ labels,
        const float* __restrict__ center, const float* __restrict__ center_label,
        const float* __restrict__ stage1_center,
        const float* __restrict__ heading_scores,
        const float* __restrict__ hres_norm, const float* __restrict__ hres,
        const int* __restrict__ hcls_label, const float* __restrict__ hres_label,
        const float* __restrict__ size_scores,
        const float* __restrict__ sres_norm, const float* __restrict__ sres,
        const int* __restrict__ scls_label, const float* __restrict__ sres_label,
        const float* __restrict__ anchors, double* __restrict__ ws,
        unsigned* __restrict__ cnt, float* __restrict__ out) {
    if (blockIdx.x >= (unsigned)kMaskBlocks) {
        batch_loss_body(blockIdx.x - kMaskBlocks, center, center_label,
                        stage1_center, heading_scores, hres_norm, hres,
                        hcls_label, hres_label, size_scores, sres_norm, sres,
                        scls_label, sres_label, anchors, ws + kMaskBlocks);
    } else {
        const int tid = blockIdx.x * kTPB + threadIdx.x;
        const vf4* __restrict__ lg4 = reinterpret_cast<const vf4*>(logits);
        const vi2* __restrict__ lb2 = reinterpret_cast<const vi2*>(labels);
        float acc = 0.f;
#pragma unroll
        for (int g = 0; g < kF4PerThread / 4; ++g) {
            vf4 a[4];
            vi2 lb[4];
#pragma unroll
            for (int i = 0; i < 4; ++i) {
                const int idx = tid + (g * 4 + i) * kMaskThreads;
                // Non-temporal: stream both arrays from HBM, zero L3 pressure.
                a[i] = __builtin_nontemporal_load(lg4 + idx);
                lb[i] = __builtin_nontemporal_load(lb2 + idx);
            }
#pragma unroll
            for (int i = 0; i < 4; ++i) {
                acc += row_nll2(a[i][0], a[i][1], lb[i][0]);
                acc += row_nll2(a[i][2], a[i][3], lb[i][1]);
            }
        }
        acc = wave_sum(acc);
        __shared__ float s[4];
        if ((threadIdx.x & 63) == 0) s[threadIdx.x >> 6] = acc;
        __syncthreads();
        if (threadIdx.x == 0)
            ws[blockIdx.x] = (double)(s[0] + s[1] + s[2] + s[3]);
    }

    // Last-block finalize: release fence -> count -> acquire fence -> reduce.
    __shared__ bool is_last;
    __threadfence();  // make this block's partial visible device-wide
    if (threadIdx.x == 0)
        is_last = (atomicAdd(cnt, 1u) == (unsigned)(kGrid - 1));
    __syncthreads();
    if (is_last) {
        __threadfence();  // acquire: order partial reads after counter
        finalize_body(ws, ws + kMaskBlocks, out);
        if (threadIdx.x == 0) atomicExch(cnt, 0u);  // reset for next replay
    }
}

extern "C" void kernel_launch(void* const* d_in, const int* in_sizes, int n_in,
                              void* d_out, int out_size, void* d_ws, size_t ws_size,
                              hipStream_t stream) {
    const float* logits = (const float*)d_in[0];
    const int* mask_label = (const int*)d_in[1];
    const float* center = (const float*)d_in[2];
    const float* center_label = (const float*)d_in[3];
    const float* stage1_center = (const float*)d_in[4];
    const float* heading_scores = (const float*)d_in[5];
    const float* hres_norm = (const float*)d_in[6];
    const float* hres = (const float*)d_in[7];
    const int* hcls_label = (const int*)d_in[8];
    const float* hres_label = (const float*)d_in[9];
    const float* size_scores = (const float*)d_in[10];
    const float* sres_norm = (const float*)d_in[11];
    const float* sres = (const float*)d_in[12];
    const int* scls_label = (const int*)d_in[13];
    const float* sres_label = (const float*)d_in[14];
    const float* anchors = (const float*)d_in[15];

    double* ws = (double*)d_ws;  // [0..4096) mask, [4096..4208) batch
    unsigned* cnt = (unsigned*)(ws + 4224);

    // Counter starts poisoned (0xAA..) / is re-zeroed by the last block; this
    // 4-byte async memset makes the first post-poison replay correct too.
    (void)hipMemsetAsync(cnt, 0, sizeof(unsigned), stream);

    fused_loss_kernel<<<kGrid, kTPB, 0, stream>>>(
        logits, mask_label, center, center_label, stage1_center, heading_scores,
        hres_norm, hres, hcls_label, hres_label, size_scores, sres_norm, sres,
        scls_label, sres_label, anchors, ws, cnt, (float*)d_out);
}

// Round 8
// 42.307 us; speedup vs baseline: 15.7644x; 15.7644x over previous
//
#include <hip/hip_runtime.h>
#include <math.h>

// FrustumPointNetLoss for MI355X (gfx950).
//
// R8: revert R7's fence-fusion (device-scope __threadfence per block = L2
//     writeback storm on 8 non-coherent XCD L2s -> 15x regression). Back to
//     the proven R5 two-dispatch structure: fused mask+batch kernel, then a
//     1-block finalize. NT loads kept on logits only (R7 proved NT does not
//     bypass L3 for reads: FETCH_SIZE unchanged; it's an eviction hint).
//     Shape change: 2048 mask blocks x 16 float4/thread so all 8 blocks/CU
//     are co-resident in one generation (4096 blocks ran as 2 ragged waves).
//
// ws layout (doubles):
//   [0 .. 2048)        mask-loss per-block partials
//   [2048 .. 2160)     batch-loss per-block partials (16 blocks x 7 sums)

constexpr int kNH = 12;
constexpr int kNS = 6;
constexpr int kBS = 4096;
constexpr int kNP = 4096;
constexpr float kPI = 3.14159265358979323846f;

constexpr int kTPB = 256;
constexpr int kMaskBlocks = 2048;
constexpr int kF4 = (kBS * kNP) / 2;             // 8,388,608 float4s (2 rows each)
constexpr int kMaskThreads = kMaskBlocks * kTPB; // 524,288
constexpr int kF4PerThread = kF4 / kMaskThreads; // 16
static_assert(kF4PerThread * kMaskThreads == kF4, "exact cover");

constexpr int kBatchBlocks = kBS / kTPB;          // 16
constexpr int kGrid = kMaskBlocks + kBatchBlocks; // 2064

typedef float vf4 __attribute__((ext_vector_type(4)));
typedef int vi2 __attribute__((ext_vector_type(2)));

__device__ __forceinline__ float wave_sum(float v) {
#pragma unroll
    for (int off = 32; off > 0; off >>= 1) v += __shfl_down(v, off, 64);
    return v;
}

__device__ __forceinline__ double wave_sum_d(double v) {
#pragma unroll
    for (int off = 32; off > 0; off >>= 1) v += __shfl_down(v, off, 64);
    return v;
}

__device__ __forceinline__ float huber_el(float e, float d) {
    float a = fabsf(e);
    float q = fminf(a, d);
    return 0.5f * q * q + d * (a - q);
}

// 2-class NLL: lse(s0,s1) - s_correct = softplus(s_other - s_correct)
__device__ __forceinline__ float row_nll2(float s0, float s1, int lb) {
    float x = lb ? (s0 - s1) : (s1 - s0);
    return fmaxf(x, 0.f) + __logf(1.f + __expf(-fabsf(x)));
}

__device__ void batch_loss_body(
        int bid,
        const float* __restrict__ center, const float* __restrict__ center_label,
        const float* __restrict__ stage1_center,
        const float* __restrict__ heading_scores,
        const float* __restrict__ hres_norm, const float* __restrict__ hres,
        const int* __restrict__ hcls_label, const float* __restrict__ hres_label,
        const float* __restrict__ size_scores,
        const float* __restrict__ sres_norm, const float* __restrict__ sres,
        const int* __restrict__ scls_label, const float* __restrict__ sres_label,
        const float* __restrict__ anchors, double* __restrict__ bpartials) {
    const int b = bid * kTPB + threadIdx.x;
    float v[7];  // center, stage1, hclass, hres, sclass, sres, corners
#pragma unroll
    for (int j = 0; j < 7; ++j) v[j] = 0.f;
    {
        const float cx = center[3 * b], cy = center[3 * b + 1], cz = center[3 * b + 2];
        const float glx = center_label[3 * b], gly = center_label[3 * b + 1],
                    glz = center_label[3 * b + 2];
        {
            float dx = cx - glx, dy = cy - gly, dz = cz - glz;
            v[0] = huber_el(sqrtf(dx * dx + dy * dy + dz * dz), 2.0f);
            float ex = cx - stage1_center[3 * b];
            float ey = cy - stage1_center[3 * b + 1];
            float ez = cz - stage1_center[3 * b + 2];
            v[1] = huber_el(sqrtf(ex * ex + ey * ey + ez * ez), 1.0f);
        }
        const int hc = hcls_label[b];
        const int sc = scls_label[b];
        {
            float m = -1e30f;
            for (int i = 0; i < kNH; ++i) m = fmaxf(m, heading_scores[b * kNH + i]);
            float se = 0.f;
            for (int i = 0; i < kNH; ++i) se += __expf(heading_scores[b * kNH + i] - m);
            v[2] = m + __logf(se) - heading_scores[b * kNH + hc];
        }
        {
            float m = -1e30f;
            for (int i = 0; i < kNS; ++i) m = fmaxf(m, size_scores[b * kNS + i]);
            float se = 0.f;
            for (int i = 0; i < kNS; ++i) se += __expf(size_scores[b * kNS + i] - m);
            v[4] = m + __logf(se) - size_scores[b * kNS + sc];
        }
        v[3] = huber_el(hres_norm[b * kNH + hc] - hres_label[b] * ((float)kNH / kPI), 1.0f);
        const float a0 = anchors[sc * 3 + 0];
        const float a1 = anchors[sc * 3 + 1];
        const float a2 = anchors[sc * 3 + 2];
        {
            float e0 = sres_label[3 * b + 0] / a0 - sres_norm[(b * kNS + sc) * 3 + 0];
            float e1 = sres_label[3 * b + 1] / a1 - sres_norm[(b * kNS + sc) * 3 + 1];
            float e2 = sres_label[3 * b + 2] / a2 - sres_norm[(b * kNS + sc) * 3 + 2];
            v[5] = huber_el(sqrtf(e0 * e0 + e1 * e1 + e2 * e2), 1.0f);
        }
        {
            const float bin = (float)hc * (2.0f * kPI / (float)kNH);
            const float hp = hres[b * kNH + hc] + bin;
            const float hg = hres_label[b] + bin;
            const float lp = a0 + 2.f * sres[(b * kNS + sc) * 3 + 0];
            const float wp = a1 + 2.f * sres[(b * kNS + sc) * 3 + 1];
            const float tp = a2 + 2.f * sres[(b * kNS + sc) * 3 + 2];
            const float lg = a0 + sres_label[3 * b + 0];
            const float wg = a1 + sres_label[3 * b + 1];
            const float tg = a2 + sres_label[3 * b + 2];
            const float cp = cosf(hp), sp = sinf(hp);
            const float cg = cosf(hg), sg = sinf(hg);
            const float SX[8] = {1, 1, -1, -1, 1, 1, -1, -1};
            const float SY[8] = {1, 1, 1, 1, -1, -1, -1, -1};
            const float SZ[8] = {1, -1, -1, 1, 1, -1, -1, 1};
            float cl = 0.f;
#pragma unroll
            for (int k = 0; k < 8; ++k) {
                float plx = 0.5f * lp * SX[k], ply = 0.5f * tp * SY[k], plz = 0.5f * wp * SZ[k];
                float px = cp * plx + sp * plz + cx;
                float py = ply + cy;
                float pz = -sp * plx + cp * plz + cz;
                float qlx = 0.5f * lg * SX[k], qly = 0.5f * tg * SY[k], qlz = 0.5f * wg * SZ[k];
                float rx = cg * qlx + sg * qlz;
                float rz = -sg * qlx + cg * qlz;
                float dgy = py - (qly + gly);
                float d1x = px - (rx + glx), d1z = pz - (rz + glz);
                float d2x = px - (-rx + glx), d2z = pz - (-rz + glz);
                float n1 = sqrtf(d1x * d1x + dgy * dgy + d1z * d1z);
                float n2 = sqrtf(d2x * d2x + dgy * dgy + d2z * d2z);
                cl += huber_el(fminf(n1, n2), 1.0f);
            }
            v[6] = cl;
        }
    }
    __shared__ float s[4][7];
#pragma unroll
    for (int j = 0; j < 7; ++j) {
        float r = wave_sum(v[j]);
        if ((threadIdx.x & 63) == 0) s[threadIdx.x >> 6][j] = r;
    }
    __syncthreads();
    if (threadIdx.x == 0) {
#pragma unroll
        for (int j = 0; j < 7; ++j)
            bpartials[bid * 7 + j] = (double)(s[0][j] + s[1][j] + s[2][j] + s[3][j]);
    }
}

__global__ __launch_bounds__(256) void fused_loss_kernel(
        const float* __restrict__ logits, const int* __restrict__ labels,
        const float* __restrict__ center, const float* __restrict__ center_label,
        const float* __restrict__ stage1_center,
        const float* __restrict__ heading_scores,
        const float* __restrict__ hres_norm, const float* __restrict__ hres,
        const int* __restrict__ hcls_label, const float* __restrict__ hres_label,
        const float* __restrict__ size_scores,
        const float* __restrict__ sres_norm, const float* __restrict__ sres,
        const int* __restrict__ scls_label, const float* __restrict__ sres_label,
        const float* __restrict__ anchors, double* __restrict__ ws) {
    if (blockIdx.x >= (unsigned)kMaskBlocks) {
        batch_loss_body(blockIdx.x - kMaskBlocks, center, center_label,
                        stage1_center, heading_scores, hres_norm, hres,
                        hcls_label, hres_label, size_scores, sres_norm, sres,
                        scls_label, sres_label, anchors, ws + kMaskBlocks);
        return;
    }
    const int tid = blockIdx.x * kTPB + threadIdx.x;
    const vf4* __restrict__ lg4 = reinterpret_cast<const vf4*>(logits);
    const vi2* __restrict__ lb2 = reinterpret_cast<const vi2*>(labels);
    float acc = 0.f;
#pragma unroll
    for (int g = 0; g < kF4PerThread / 4; ++g) {
        vf4 a[4];
        vi2 lb[4];
#pragma unroll
        for (int i = 0; i < 4; ++i) {
            const int idx = tid + (g * 4 + i) * kMaskThreads;
            // NT on logits: evict-first hint keeps the 128 MB stream from
            // thrashing L3's retention of labels (R7: NT does NOT cut FETCH).
            a[i] = __builtin_nontemporal_load(lg4 + idx);
            lb[i] = lb2[idx];  // labels: normal cached load
        }
#pragma unroll
        for (int i = 0; i < 4; ++i) {
            acc += row_nll2(a[i][0], a[i][1], lb[i][0]);
            acc += row_nll2(a[i][2], a[i][3], lb[i][1]);
        }
    }
    acc = wave_sum(acc);
    __shared__ float s[4];
    if ((threadIdx.x & 63) == 0) s[threadIdx.x >> 6] = acc;
    __syncthreads();
    if (threadIdx.x == 0)
        ws[blockIdx.x] = (double)(s[0] + s[1] + s[2] + s[3]);
}

__global__ __launch_bounds__(256) void finalize_kernel(
        const double* __restrict__ partials, const double* __restrict__ bpartials,
        float* __restrict__ out) {
    double acc = 0.0;
#pragma unroll
    for (int i = 0; i < kMaskBlocks / kTPB; ++i)
        acc += partials[threadIdx.x + i * kTPB];
    acc = wave_sum_d(acc);
    __shared__ double s[4];
    if ((threadIdx.x & 63) == 0) s[threadIdx.x >> 6] = acc;
    __syncthreads();
    if (threadIdx.x == 0) {
        const double mask_sum = s[0] + s[1] + s[2] + s[3];
        double bsum[7] = {0, 0, 0, 0, 0, 0, 0};
        for (int blk = 0; blk < kBatchBlocks; ++blk)
#pragma unroll
            for (int j = 0; j < 7; ++j) bsum[j] += bpartials[blk * 7 + j];
        const double inv_rows = 1.0 / ((double)kBS * (double)kNP);
        const double inv_bs = 1.0 / (double)kBS;
        float mask_l = (float)(mask_sum * inv_rows);
        float center_l = (float)(bsum[0] * inv_bs);
        float stage1_l = (float)(bsum[1] * inv_bs);
        float hclass_l = (float)(bsum[2] * inv_bs);
        float hres_l20 = (float)(bsum[3] * inv_bs * 20.0);
        float sclass_l = (float)(bsum[4] * inv_bs);
        float sres_l20 = (float)(bsum[5] * inv_bs * 20.0);
        float corners10 = (float)(bsum[6] * inv_bs * (1.0 / 8.0) * 10.0);
        float total = mask_l + center_l + hclass_l + sclass_l + hres_l20 + sres_l20 +
                      stage1_l + corners10;
        out[0] = total;
        out[1] = mask_l;
        out[2] = center_l;
        out[3] = hclass_l;
        out[4] = sclass_l;
        out[5] = hres_l20;
        out[6] = sres_l20;
        out[7] = stage1_l;
        out[8] = corners10;
    }
}

extern "C" void kernel_launch(void* const* d_in, const int* in_sizes, int n_in,
                              void* d_out, int out_size, void* d_ws, size_t ws_size,
                              hipStream_t stream) {
    const float* logits = (const float*)d_in[0];
    const int* mask_label = (const int*)d_in[1];
    const float* center = (const float*)d_in[2];
    const float* center_label = (const float*)d_in[3];
    const float* stage1_center = (const float*)d_in[4];
    const float* heading_scores = (const float*)d_in[5];
    const float* hres_norm = (const float*)d_in[6];
    const float* hres = (const float*)d_in[7];
    const int* hcls_label = (const int*)d_in[8];
    const float* hres_label = (const float*)d_in[9];
    const float* size_scores = (const float*)d_in[10];
    const float* sres_norm = (const float*)d_in[11];
    const float* sres = (const float*)d_in[12];
    const int* scls_label = (const int*)d_in[13];
    const float* sres_label = (const float*)d_in[14];
    const float* anchors = (const float*)d_in[15];

    double* ws = (double*)d_ws;  // [0..2048) mask partials, [2048..2160) batch

    fused_loss_kernel<<<kGrid, kTPB, 0, stream>>>(
        logits, mask_label, center, center_label, stage1_center, heading_scores,
        hres_norm, hres, hcls_label, hres_label, size_scores, sres_norm, sres,
        scls_label, sres_label, anchors, ws);
    finalize_kernel<<<1, kTPB, 0, stream>>>(ws, ws + kMaskBlocks, (float*)d_out);
}

// Round 9
// 40.784 us; speedup vs baseline: 16.3530x; 1.0373x over previous
//
#include <hip/hip_runtime.h>
#include <math.h>

// FrustumPointNetLoss for MI355X (gfx950).
//
// R9: (1) grid = exactly 2048 (one co-resident generation; 8 blocks/CU x 256
//     CU). R8's 2064-block grid ran the 16 batch blocks as a serialized
//     second-generation tail. Now blocks 0..15 do the batch body as extra
//     duty BEFORE their mask work -- trig/VALU overlaps other blocks' streams.
//     (2) NT hint dropped: timed replays have no poison fills between them,
//     so the 192 MB footprint can stay L3-resident (256 MB) across replays;
//     evict-first on logits would throw away 128 MB of that retention.
//
// ws layout (doubles):
//   [0 .. 2048)        mask-loss per-block partials
//   [2048 .. 2160)     batch-loss per-block partials (16 blocks x 7 sums)

constexpr int kNH = 12;
constexpr int kNS = 6;
constexpr int kBS = 4096;
constexpr int kNP = 4096;
constexpr float kPI = 3.14159265358979323846f;

constexpr int kTPB = 256;
constexpr int kMaskBlocks = 2048;                // == grid; one generation
constexpr int kF4 = (kBS * kNP) / 2;             // 8,388,608 float4s (2 rows each)
constexpr int kMaskThreads = kMaskBlocks * kTPB; // 524,288
constexpr int kF4PerThread = kF4 / kMaskThreads; // 16
static_assert(kF4PerThread * kMaskThreads == kF4, "exact cover");

constexpr int kBatchBlocks = kBS / kTPB;         // 16

typedef float vf4 __attribute__((ext_vector_type(4)));
typedef int vi2 __attribute__((ext_vector_type(2)));

__device__ __forceinline__ float wave_sum(float v) {
#pragma unroll
    for (int off = 32; off > 0; off >>= 1) v += __shfl_down(v, off, 64);
    return v;
}

__device__ __forceinline__ double wave_sum_d(double v) {
#pragma unroll
    for (int off = 32; off > 0; off >>= 1) v += __shfl_down(v, off, 64);
    return v;
}

__device__ __forceinline__ float huber_el(float e, float d) {
    float a = fabsf(e);
    float q = fminf(a, d);
    return 0.5f * q * q + d * (a - q);
}

// 2-class NLL: lse(s0,s1) - s_correct = softplus(s_other - s_correct)
__device__ __forceinline__ float row_nll2(float s0, float s1, int lb) {
    float x = lb ? (s0 - s1) : (s1 - s0);
    return fmaxf(x, 0.f) + __logf(1.f + __expf(-fabsf(x)));
}

__device__ void batch_loss_body(
        int bid,
        const float* __restrict__ center, const float* __restrict__ center_label,
        const float* __restrict__ stage1_center,
        const float* __restrict__ heading_scores,
        const float* __restrict__ hres_norm, const float* __restrict__ hres,
        const int* __restrict__ hcls_label, const float* __restrict__ hres_label,
        const float* __restrict__ size_scores,
        const float* __restrict__ sres_norm, const float* __restrict__ sres,
        const int* __restrict__ scls_label, const float* __restrict__ sres_label,
        const float* __restrict__ anchors, double* __restrict__ bpartials) {
    const int b = bid * kTPB + threadIdx.x;
    float v[7];  // center, stage1, hclass, hres, sclass, sres, corners
#pragma unroll
    for (int j = 0; j < 7; ++j) v[j] = 0.f;
    {
        const float cx = center[3 * b], cy = center[3 * b + 1], cz = center[3 * b + 2];
        const float glx = center_label[3 * b], gly = center_label[3 * b + 1],
                    glz = center_label[3 * b + 2];
        {
            float dx = cx - glx, dy = cy - gly, dz = cz - glz;
            v[0] = huber_el(sqrtf(dx * dx + dy * dy + dz * dz), 2.0f);
            float ex = cx - stage1_center[3 * b];
            float ey = cy - stage1_center[3 * b + 1];
            float ez = cz - stage1_center[3 * b + 2];
            v[1] = huber_el(sqrtf(ex * ex + ey * ey + ez * ez), 1.0f);
        }
        const int hc = hcls_label[b];
        const int sc = scls_label[b];
        {
            float m = -1e30f;
            for (int i = 0; i < kNH; ++i) m = fmaxf(m, heading_scores[b * kNH + i]);
            float se = 0.f;
            for (int i = 0; i < kNH; ++i) se += __expf(heading_scores[b * kNH + i] - m);
            v[2] = m + __logf(se) - heading_scores[b * kNH + hc];
        }
        {
            float m = -1e30f;
            for (int i = 0; i < kNS; ++i) m = fmaxf(m, size_scores[b * kNS + i]);
            float se = 0.f;
            for (int i = 0; i < kNS; ++i) se += __expf(size_scores[b * kNS + i] - m);
            v[4] = m + __logf(se) - size_scores[b * kNS + sc];
        }
        v[3] = huber_el(hres_norm[b * kNH + hc] - hres_label[b] * ((float)kNH / kPI), 1.0f);
        const float a0 = anchors[sc * 3 + 0];
        const float a1 = anchors[sc * 3 + 1];
        const float a2 = anchors[sc * 3 + 2];
        {
            float e0 = sres_label[3 * b + 0] / a0 - sres_norm[(b * kNS + sc) * 3 + 0];
            float e1 = sres_label[3 * b + 1] / a1 - sres_norm[(b * kNS + sc) * 3 + 1];
            float e2 = sres_label[3 * b + 2] / a2 - sres_norm[(b * kNS + sc) * 3 + 2];
            v[5] = huber_el(sqrtf(e0 * e0 + e1 * e1 + e2 * e2), 1.0f);
        }
        {
            const float bin = (float)hc * (2.0f * kPI / (float)kNH);
            const float hp = hres[b * kNH + hc] + bin;
            const float hg = hres_label[b] + bin;
            const float lp = a0 + 2.f * sres[(b * kNS + sc) * 3 + 0];
            const float wp = a1 + 2.f * sres[(b * kNS + sc) * 3 + 1];
            const float tp = a2 + 2.f * sres[(b * kNS + sc) * 3 + 2];
            const float lg = a0 + sres_label[3 * b + 0];
            const float wg = a1 + sres_label[3 * b + 1];
            const float tg = a2 + sres_label[3 * b + 2];
            const float cp = cosf(hp), sp = sinf(hp);
            const float cg = cosf(hg), sg = sinf(hg);
            const float SX[8] = {1, 1, -1, -1, 1, 1, -1, -1};
            const float SY[8] = {1, 1, 1, 1, -1, -1, -1, -1};
            const float SZ[8] = {1, -1, -1, 1, 1, -1, -1, 1};
            float cl = 0.f;
#pragma unroll
            for (int k = 0; k < 8; ++k) {
                float plx = 0.5f * lp * SX[k], ply = 0.5f * tp * SY[k], plz = 0.5f * wp * SZ[k];
                float px = cp * plx + sp * plz + cx;
                float py = ply + cy;
                float pz = -sp * plx + cp * plz + cz;
                float qlx = 0.5f * lg * SX[k], qly = 0.5f * tg * SY[k], qlz = 0.5f * wg * SZ[k];
                float rx = cg * qlx + sg * qlz;
                float rz = -sg * qlx + cg * qlz;
                float dgy = py - (qly + gly);
                float d1x = px - (rx + glx), d1z = pz - (rz + glz);
                float d2x = px - (-rx + glx), d2z = pz - (-rz + glz);
                float n1 = sqrtf(d1x * d1x + dgy * dgy + d1z * d1z);
                float n2 = sqrtf(d2x * d2x + dgy * dgy + d2z * d2z);
                cl += huber_el(fminf(n1, n2), 1.0f);
            }
            v[6] = cl;
        }
    }
    __shared__ float sb[4][7];
#pragma unroll
    for (int j = 0; j < 7; ++j) {
        float r = wave_sum(v[j]);
        if ((threadIdx.x & 63) == 0) sb[threadIdx.x >> 6][j] = r;
    }
    __syncthreads();
    if (threadIdx.x == 0) {
#pragma unroll
        for (int j = 0; j < 7; ++j)
            bpartials[bid * 7 + j] = (double)(sb[0][j] + sb[1][j] + sb[2][j] + sb[3][j]);
    }
    __syncthreads();  // sb reuse safety before mask phase
}

__global__ __launch_bounds__(256) void fused_loss_kernel(
        const float* __restrict__ logits, const int* __restrict__ labels,
        const float* __restrict__ center, const float* __restrict__ center_label,
        const float* __restrict__ stage1_center,
        const float* __restrict__ heading_scores,
        const float* __restrict__ hres_norm, const float* __restrict__ hres,
        const int* __restrict__ hcls_label, const float* __restrict__ hres_label,
        const float* __restrict__ size_scores,
        const float* __restrict__ sres_norm, const float* __restrict__ sres,
        const int* __restrict__ scls_label, const float* __restrict__ sres_label,
        const float* __restrict__ anchors, double* __restrict__ ws) {
    // Blocks 0..15 additionally handle the per-batch losses (overlapped with
    // the other 2032 blocks' streaming; keeps grid at exactly one generation).
    if (blockIdx.x < (unsigned)kBatchBlocks) {
        batch_loss_body(blockIdx.x, center, center_label, stage1_center,
                        heading_scores, hres_norm, hres, hcls_label, hres_label,
                        size_scores, sres_norm, sres, scls_label, sres_label,
                        anchors, ws + kMaskBlocks);
    }
    const int tid = blockIdx.x * kTPB + threadIdx.x;
    const vf4* __restrict__ lg4 = reinterpret_cast<const vf4*>(logits);
    const vi2* __restrict__ lb2 = reinterpret_cast<const vi2*>(labels);
    float acc = 0.f;
#pragma unroll
    for (int g = 0; g < kF4PerThread / 4; ++g) {
        vf4 a[4];
        vi2 lb[4];
#pragma unroll
        for (int i = 0; i < 4; ++i) {
            const int idx = tid + (g * 4 + i) * kMaskThreads;
            a[i] = lg4[idx];   // plain cached loads: let L3 retain across replays
            lb[i] = lb2[idx];
        }
#pragma unroll
        for (int i = 0; i < 4; ++i) {
            acc += row_nll2(a[i][0], a[i][1], lb[i][0]);
            acc += row_nll2(a[i][2], a[i][3], lb[i][1]);
        }
    }
    acc = wave_sum(acc);
    __shared__ float s[4];
    if ((threadIdx.x & 63) == 0) s[threadIdx.x >> 6] = acc;
    __syncthreads();
    if (threadIdx.x == 0)
        ws[blockIdx.x] = (double)(s[0] + s[1] + s[2] + s[3]);
}

__global__ __launch_bounds__(256) void finalize_kernel(
        const double* __restrict__ partials, const double* __restrict__ bpartials,
        float* __restrict__ out) {
    double acc = 0.0;
#pragma unroll
    for (int i = 0; i < kMaskBlocks / kTPB; ++i)
        acc += partials[threadIdx.x + i * kTPB];
    acc = wave_sum_d(acc);
    __shared__ double s[4];
    if ((threadIdx.x & 63) == 0) s[threadIdx.x >> 6] = acc;
    __syncthreads();
    if (threadIdx.x == 0) {
        const double mask_sum = s[0] + s[1] + s[2] + s[3];
        double bsum[7] = {0, 0, 0, 0, 0, 0, 0};
        for (int blk = 0; blk < kBatchBlocks; ++blk)
#pragma unroll
            for (int j = 0; j < 7; ++j) bsum[j] += bpartials[blk * 7 + j];
        const double inv_rows = 1.0 / ((double)kBS * (double)kNP);
        const double inv_bs = 1.0 / (double)kBS;
        float mask_l = (float)(mask_sum * inv_rows);
        float center_l = (float)(bsum[0] * inv_bs);
        float stage1_l = (float)(bsum[1] * inv_bs);
        float hclass_l = (float)(bsum[2] * inv_bs);
        float hres_l20 = (float)(bsum[3] * inv_bs * 20.0);
        float sclass_l = (float)(bsum[4] * inv_bs);
        float sres_l20 = (float)(bsum[5] * inv_bs * 20.0);
        float corners10 = (float)(bsum[6] * inv_bs * (1.0 / 8.0) * 10.0);
        float total = mask_l + center_l + hclass_l + sclass_l + hres_l20 + sres_l20 +
                      stage1_l + corners10;
        out[0] = total;
        out[1] = mask_l;
        out[2] = center_l;
        out[3] = hclass_l;
        out[4] = sclass_l;
        out[5] = hres_l20;
        out[6] = sres_l20;
        out[7] = stage1_l;
        out[8] = corners10;
    }
}

extern "C" void kernel_launch(void* const* d_in, const int* in_sizes, int n_in,
                              void* d_out, int out_size, void* d_ws, size_t ws_size,
                              hipStream_t stream) {
    const float* logits = (const float*)d_in[0];
    const int* mask_label = (const int*)d_in[1];
    const float* center = (const float*)d_in[2];
    const float* center_label = (const float*)d_in[3];
    const float* stage1_center = (const float*)d_in[4];
    const float* heading_scores = (const float*)d_in[5];
    const float* hres_norm = (const float*)d_in[6];
    const float* hres = (const float*)d_in[7];
    const int* hcls_label = (const int*)d_in[8];
    const float* hres_label = (const float*)d_in[9];
    const float* size_scores = (const float*)d_in[10];
    const float* sres_norm = (const float*)d_in[11];
    const float* sres = (const float*)d_in[12];
    const int* scls_label = (const int*)d_in[13];
    const float* sres_label = (const float*)d_in[14];
    const float* anchors = (const float*)d_in[15];

    double* ws = (double*)d_ws;  // [0..2048) mask partials, [2048..2160) batch

    fused_loss_kernel<<<kMaskBlocks, kTPB, 0, stream>>>(
        logits, mask_label, center, center_label, stage1_center, heading_scores,
        hres_norm, hres, hcls_label, hres_label, size_scores, sres_norm, sres,
        scls_label, sres_label, anchors, ws);
    finalize_kernel<<<1, kTPB, 0, stream>>>(ws, ws + kMaskBlocks, (float*)d_out);
}